// Round 1
// baseline (566.024 us; speedup 1.0000x reference)
//
#include <hip/hip_runtime.h>

typedef __attribute__((ext_vector_type(8))) short short8;
typedef __attribute__((ext_vector_type(4))) float f32x4;
typedef unsigned short ushort_t;
typedef unsigned int u32;
typedef unsigned long long u64;

#define MFMA16(a,b,c) __builtin_amdgcn_mfma_f32_16x16x32_bf16((a),(b),(c),0,0,0)

__device__ __forceinline__ ushort_t f2bf(float f){
  union { float f; u32 u; } v; v.f = f;
  u32 r = v.u + 0x7fffu + ((v.u >> 16) & 1u);
  return (ushort_t)(r >> 16);
}
__device__ __forceinline__ float bf2f(ushort_t h){
  union { u32 u; float f; } v; v.u = ((u32)h) << 16; return v.f;
}
__device__ __forceinline__ u64 pack4(float a, float b, float c, float d){
  u32 p0 = (u32)f2bf(a) | ((u32)f2bf(b) << 16);
  u32 p1 = (u32)f2bf(c) | ((u32)f2bf(d) << 16);
  return (u64)p0 | ((u64)p1 << 32);
}

template<int CTRL>
__device__ __forceinline__ float dpp_add(float x){
  union { float f; int i; } a, b;
  a.f = x;
  b.i = __builtin_amdgcn_update_dpp(a.i, a.i, CTRL, 0xF, 0xF, false);
  return x + b.f;
}
__device__ __forceinline__ float red4_add(float x){
  x = dpp_add<0xB1>(x); x = dpp_add<0x4E>(x);
  return x;
}

// B=4096 T=32 C=180 H=6 HD=30 ; tokens=131072
// ws (ushort): wqkv[6][3][32][192] | w1t[768][192] | w2t[192][768]
#define WQKV_ELEMS (576*192)
#define W1T_ELEMS  (768*192)
#define W2T_ELEMS  (192*768)

// LDS strides (ushorts). All rows 16B-aligned; bank-stride 2-way max (free, m136).
#define SH 200   // 400B rows: hn / x-stage / x2 / act   (bank stride 4)
#define SS 40    //  80B rows: attn scratch tiles        (bank stride 20)
#define SA 196   // 392B rows: att out                   (bank stride 2)

__global__ void prep_weights(const float* __restrict__ wq, const float* __restrict__ wk,
                             const float* __restrict__ wv, const float* __restrict__ w1,
                             const float* __restrict__ w2, ushort_t* __restrict__ ws){
  ushort_t* wqkv = ws;
  ushort_t* w1t = ws + WQKV_ELEMS;
  ushort_t* w2t = w1t + W1T_ELEMS;
  int tid = blockIdx.x * blockDim.x + threadIdx.x;
  int stride = gridDim.x * blockDim.x;
  for (int i = tid; i < WQKV_ELEMS; i += stride){
    int k = i % 192; int row = i / 192;
    int d = row & 31; int m = (row >> 5) % 3; int h = row / 96;
    float v = 0.f;
    if (d < 30 && k < 180){
      const float* W = (m == 0) ? wq : ((m == 1) ? wk : wv);
      v = W[(h*180 + k)*30 + d];
    }
    wqkv[i] = f2bf(v);
  }
  for (int i = tid; i < W1T_ELEMS; i += stride){
    int c = i % 192; int n = i / 192;
    float v = (n < 720 && c < 180) ? w1[c*720 + n] : 0.f;
    w1t[i] = f2bf(v);
  }
  for (int i = tid; i < W2T_ELEMS; i += stride){
    int c4 = i % 768; int n = i / 768;
    float v = (n < 180 && c4 < 720) ? w2[c4*180 + n] : 0.f;
    w2t[i] = f2bf(v);
  }
}

// ---------------- Fused kernel: 1 batch (32 tokens) per block, 4 waves.
// LDS: regA 15360B (x-stage | 3x wave attn scratch | x2 | act) + hn 12800B + att 12544B
//      = 40704B -> 4 blocks/CU (vs 2 before). Waves 0-2 each do 2 heads in attn.
__global__ __launch_bounds__(256, 4)
void block_kernel(const float* __restrict__ x,
                  const float* __restrict__ g1, const float* __restrict__ be1,
                  const float* __restrict__ g2, const float* __restrict__ be2,
                  const float* __restrict__ b1, const float* __restrict__ b2,
                  const ushort_t* __restrict__ wqkv, const ushort_t* __restrict__ w1t,
                  const ushort_t* __restrict__ w2t, float* __restrict__ out){
  __shared__ __align__(16) ushort_t regA[7680];    // 15360B multi-use region
  __shared__ __align__(16) ushort_t hn[32*SH];     // ln1 out -> ln2 out -> mlp out
  __shared__ __align__(16) ushort_t att[32*SA];    // attn out [t][head*32+d]

  int tid = threadIdx.x;
  int wave = tid >> 6, lane = tid & 63;
  int quad = lane >> 4, c16 = lane & 15;
  long base = (long)blockIdx.x * 5760;   // 32 tokens * 180

  // ---- stage x -> regA bf16 (cols 180..191 zeroed); 1440 f32x4 + 96 pad u64 = 1536 jobs
  #pragma unroll
  for (int it = 0; it < 6; it++){
    int idx = it*256 + tid;
    if (idx < 1440){
      f32x4 v = *(const f32x4*)(x + base + (long)idx*4);
      int row = (int)(((u32)idx * 745655u) >> 25);   // idx/45
      int col = idx - row*45;
      *(u64*)(regA + row*SH + col*4) = pack4(v.x, v.y, v.z, v.w);
    } else {
      int p = idx - 1440;                 // [0,96)
      int row = (p*21846) >> 16;          // p/3
      int g = p - row*3;
      *(u64*)(regA + row*SH + 180 + g*4) = 0ull;
    }
  }
  __syncthreads();

  // ---- LN1: 8 threads/row, 24 cols each (pad zeros included; /180 fixed)
  {
    int row = tid >> 3, sub = tid & 7;
    int c0 = sub*24;
    float s1 = 0.f, s2 = 0.f;
    #pragma unroll
    for (int gi = 0; gi < 6; gi++){
      u64 m = *(const u64*)(regA + row*SH + c0 + gi*4);
      #pragma unroll
      for (int e = 0; e < 4; e++){
        float v = bf2f((ushort_t)(m >> (16*e)));
        s1 += v; s2 += v*v;
      }
    }
    s1 = red4_add(s1); s1 += __shfl_xor(s1, 4);
    s2 = red4_add(s2); s2 += __shfl_xor(s2, 4);
    float mu = s1 * (1.f/180.f);
    float rstd = rsqrtf(s2 * (1.f/180.f) - mu*mu + 1e-5f);
    #pragma unroll
    for (int gi = 0; gi < 6; gi++){
      int c = c0 + gi*4;
      if (c < 180){
        u64 m = *(const u64*)(regA + row*SH + c);
        f32x4 g = *(const f32x4*)(g1 + c);
        f32x4 be = *(const f32x4*)(be1 + c);
        float v0 = (bf2f((ushort_t)(m    )) - mu)*rstd*g.x + be.x;
        float v1 = (bf2f((ushort_t)(m>>16)) - mu)*rstd*g.y + be.y;
        float v2 = (bf2f((ushort_t)(m>>32)) - mu)*rstd*g.z + be.z;
        float v3 = (bf2f((ushort_t)(m>>48)) - mu)*rstd*g.w + be.w;
        *(u64*)(hn + row*SH + c) = pack4(v0, v1, v2, v3);
      } else {
        *(u64*)(hn + row*SH + c) = 0ull;
      }
    }
  }
  __syncthreads();

  // ---- attention: waves 0-2 -> heads {2w, 2w+1}; scratch overlays regA (x-stage dead)
  if (wave < 3){
    ushort_t* buf0 = regA + wave*2560;   // q, then vT  (32 x SS)
    ushort_t* buf1 = buf0 + 32*SS;       // k, then P
    const float scl = 0.18257418583505537f;  // 30^-0.5

    #pragma unroll
    for (int hh = 0; hh < 2; hh++){
      int head = wave*2 + hh;
      const ushort_t* wbase = wqkv + head*(96*192);

      f32x4 accq[2][2], acck[2][2], accv[2][2];
      #pragma unroll
      for (int i = 0; i < 2; i++)
        #pragma unroll
        for (int j = 0; j < 2; j++){ accq[i][j]=(f32x4)0.f; acck[i][j]=(f32x4)0.f; accv[i][j]=(f32x4)0.f; }

      #pragma unroll
      for (int kk = 0; kk < 6; kk++){
        short8 hf[2], aq[2], ak[2], av[2];
        #pragma unroll
        for (int nt = 0; nt < 2; nt++)
          hf[nt] = *(const short8*)(hn + (nt*16 + c16)*SH + kk*32 + quad*8);
        #pragma unroll
        for (int mt = 0; mt < 2; mt++){
          aq[mt] = *(const short8*)(wbase + (      mt*16 + c16)*192 + kk*32 + quad*8);
          ak[mt] = *(const short8*)(wbase + (32  + mt*16 + c16)*192 + kk*32 + quad*8);
          av[mt] = *(const short8*)(wbase + (64  + mt*16 + c16)*192 + kk*32 + quad*8);
        }
        #pragma unroll
        for (int mt = 0; mt < 2; mt++)
          #pragma unroll
          for (int nt = 0; nt < 2; nt++){
            accq[mt][nt] = MFMA16(aq[mt], hf[nt], accq[mt][nt]);  // C[d][t] = qT
            acck[mt][nt] = MFMA16(ak[mt], hf[nt], acck[mt][nt]);  // C[d][t] = kT
            accv[mt][nt] = MFMA16(hf[mt], av[nt], accv[mt][nt]);  // C[t][d] = v
          }
      }
      // q,k rowmajor [t][d] into scratch
      #pragma unroll
      for (int mt = 0; mt < 2; mt++)
        #pragma unroll
        for (int nt = 0; nt < 2; nt++){
          *(u64*)(buf0 + (nt*16 + c16)*SS + mt*16 + quad*4) =
            pack4(accq[mt][nt][0], accq[mt][nt][1], accq[mt][nt][2], accq[mt][nt][3]);
          *(u64*)(buf1 + (nt*16 + c16)*SS + mt*16 + quad*4) =
            pack4(acck[mt][nt][0], acck[mt][nt][1], acck[mt][nt][2], acck[mt][nt][3]);
        }
      // S^T = MFMA(A=k, B=q): C[s][t]
      f32x4 sacc[2][2];
      #pragma unroll
      for (int i = 0; i < 2; i++){ sacc[i][0]=(f32x4)0.f; sacc[i][1]=(f32x4)0.f; }
      short8 akf[2], bqf[2];
      #pragma unroll
      for (int mt = 0; mt < 2; mt++) akf[mt] = *(const short8*)(buf1 + (mt*16 + c16)*SS + quad*8);
      #pragma unroll
      for (int nt = 0; nt < 2; nt++) bqf[nt] = *(const short8*)(buf0 + (nt*16 + c16)*SS + quad*8);
      #pragma unroll
      for (int mt = 0; mt < 2; mt++)
        #pragma unroll
        for (int nt = 0; nt < 2; nt++)
          sacc[mt][nt] = MFMA16(akf[mt], bqf[nt], sacc[mt][nt]);
      // softmax: lane owns token t=nt*16+c16; reduce over quads (xor16,32)
      #pragma unroll
      for (int nt = 0; nt < 2; nt++){
        int t = nt*16 + c16;
        float v[8];
        #pragma unroll
        for (int r = 0; r < 4; r++){
          int s0 = quad*4 + r, s1v = 16 + quad*4 + r;
          v[r]   = (s0  > t) ? -1e30f : sacc[0][nt][r]*scl;
          v[4+r] = (s1v > t) ? -1e30f : sacc[1][nt][r]*scl;
        }
        float m = v[0];
        #pragma unroll
        for (int i = 1; i < 8; i++) m = fmaxf(m, v[i]);
        m = fmaxf(m, __shfl_xor(m, 16));
        m = fmaxf(m, __shfl_xor(m, 32));
        float e[8], s = 0.f;
        #pragma unroll
        for (int i = 0; i < 8; i++){ e[i] = __expf(v[i] - m); s += e[i]; }
        s += __shfl_xor(s, 16);
        s += __shfl_xor(s, 32);
        float inv = 1.f / s;
        *(u64*)(buf1 + t*SS +      quad*4) = pack4(e[0]*inv, e[1]*inv, e[2]*inv, e[3]*inv);
        *(u64*)(buf1 + t*SS + 16 + quad*4) = pack4(e[4]*inv, e[5]*inv, e[6]*inv, e[7]*inv);
      }
      // vT [d][t] into buf0 (q consumed)
      #pragma unroll
      for (int mt = 0; mt < 2; mt++)
        #pragma unroll
        for (int nt = 0; nt < 2; nt++)
          *(u64*)(buf0 + (nt*16 + c16)*SS + mt*16 + quad*4) =
            pack4(accv[mt][nt][0], accv[mt][nt][1], accv[mt][nt][2], accv[mt][nt][3]);
      // PV: C[d][t] = MFMA(A=vT, B=P)
      f32x4 oacc[2][2];
      #pragma unroll
      for (int i = 0; i < 2; i++){ oacc[i][0]=(f32x4)0.f; oacc[i][1]=(f32x4)0.f; }
      short8 avf[2], bpf[2];
      #pragma unroll
      for (int mt = 0; mt < 2; mt++) avf[mt] = *(const short8*)(buf0 + (mt*16 + c16)*SS + quad*8);
      #pragma unroll
      for (int nt = 0; nt < 2; nt++) bpf[nt] = *(const short8*)(buf1 + (nt*16 + c16)*SS + quad*8);
      #pragma unroll
      for (int mt = 0; mt < 2; mt++)
        #pragma unroll
        for (int nt = 0; nt < 2; nt++)
          oacc[mt][nt] = MFMA16(avf[mt], bpf[nt], oacc[mt][nt]);
      // att[t][head*32+d]
      #pragma unroll
      for (int mt = 0; mt < 2; mt++)
        #pragma unroll
        for (int nt = 0; nt < 2; nt++)
          *(u64*)(att + (nt*16 + c16)*SA + head*32 + mt*16 + quad*4) =
            pack4(oacc[mt][nt][0], oacc[mt][nt][1], oacc[mt][nt][2], oacc[mt][nt][3]);
    }
  }
  __syncthreads();

  // ---- x2 = x + att -> regA bf16 (LN2 input; never materialized in global)
  #pragma unroll
  for (int it = 0; it < 6; it++){
    int idx = it*256 + tid;
    if (idx < 1440){
      f32x4 v = *(const f32x4*)(x + base + (long)idx*4);
      int row = (int)(((u32)idx * 745655u) >> 25);
      int col4 = (idx - row*45)*4;
      #pragma unroll
      for (int e = 0; e < 4; e++){
        int c = col4 + e;
        int h = (c*4370) >> 17;     // c/30
        int d = c - h*30;
        v[e] += bf2f(att[row*SA + h*32 + d]);
      }
      *(u64*)(regA + row*SH + col4) = pack4(v.x, v.y, v.z, v.w);
    } else {
      int p = idx - 1440;
      int row = (p*21846) >> 16;
      int g = p - row*3;
      *(u64*)(regA + row*SH + 180 + g*4) = 0ull;
    }
  }
  __syncthreads();

  // ---- LN2: regA -> hn
  {
    int row = tid >> 3, sub = tid & 7;
    int c0 = sub*24;
    float s1 = 0.f, s2 = 0.f;
    #pragma unroll
    for (int gi = 0; gi < 6; gi++){
      u64 m = *(const u64*)(regA + row*SH + c0 + gi*4);
      #pragma unroll
      for (int e = 0; e < 4; e++){
        float v = bf2f((ushort_t)(m >> (16*e)));
        s1 += v; s2 += v*v;
      }
    }
    s1 = red4_add(s1); s1 += __shfl_xor(s1, 4);
    s2 = red4_add(s2); s2 += __shfl_xor(s2, 4);
    float mu = s1 * (1.f/180.f);
    float rstd = rsqrtf(s2 * (1.f/180.f) - mu*mu + 1e-5f);
    #pragma unroll
    for (int gi = 0; gi < 6; gi++){
      int c = c0 + gi*4;
      if (c < 180){
        u64 m = *(const u64*)(regA + row*SH + c);
        f32x4 g = *(const f32x4*)(g2 + c);
        f32x4 be = *(const f32x4*)(be2 + c);
        float v0 = (bf2f((ushort_t)(m    )) - mu)*rstd*g.x + be.x;
        float v1 = (bf2f((ushort_t)(m>>16)) - mu)*rstd*g.y + be.y;
        float v2 = (bf2f((ushort_t)(m>>32)) - mu)*rstd*g.z + be.z;
        float v3 = (bf2f((ushort_t)(m>>48)) - mu)*rstd*g.w + be.w;
        *(u64*)(hn + row*SH + c) = pack4(v0, v1, v2, v3);
      } else {
        *(u64*)(hn + row*SH + c) = 0ull;
      }
    }
  }
  __syncthreads();

  // ---- MLP: 4 chunks of 192 hidden; act overlays regA (x2 dead after LN2)
  {
    ushort_t* act = regA;
    f32x4 outacc[3][2];
    #pragma unroll
    for (int i = 0; i < 3; i++)
      #pragma unroll
      for (int j = 0; j < 2; j++) outacc[i][j] = (f32x4)0.f;

    for (int ch = 0; ch < 4; ch++){
      // MLP1: C[n][t] = MFMA(A=w1 rows n, B=hn rows t)
      f32x4 aacc[3][2];
      #pragma unroll
      for (int i = 0; i < 3; i++)
        #pragma unroll
        for (int j = 0; j < 2; j++) aacc[i][j] = (f32x4)0.f;
      #pragma unroll
      for (int kk = 0; kk < 6; kk++){
        short8 bh[2];
        #pragma unroll
        for (int tt = 0; tt < 2; tt++)
          bh[tt] = *(const short8*)(hn + (tt*16 + c16)*SH + kk*32 + quad*8);
        short8 aw[3];
        #pragma unroll
        for (int mi = 0; mi < 3; mi++)
          aw[mi] = *(const short8*)(w1t + (size_t)(ch*192 + (wave*3+mi)*16 + c16)*192 + kk*32 + quad*8);
        #pragma unroll
        for (int mi = 0; mi < 3; mi++)
          #pragma unroll
          for (int tt = 0; tt < 2; tt++)
            aacc[mi][tt] = MFMA16(aw[mi], bh[tt], aacc[mi][tt]);
      }
      __syncthreads();   // prev chunk's MLP2 done reading act
      // bias + relu + packed store act[t][n]
      #pragma unroll
      for (int mi = 0; mi < 3; mi++){
        int nrel = (wave*3+mi)*16 + quad*4;
        int nabs = ch*192 + nrel;
        f32x4 bias = (f32x4)0.f;
        if (nabs < 720) bias = *(const f32x4*)(b1 + nabs);
        #pragma unroll
        for (int tt = 0; tt < 2; tt++){
          float v0 = fmaxf(aacc[mi][tt][0] + bias[0], 0.f);
          float v1 = fmaxf(aacc[mi][tt][1] + bias[1], 0.f);
          float v2 = fmaxf(aacc[mi][tt][2] + bias[2], 0.f);
          float v3 = fmaxf(aacc[mi][tt][3] + bias[3], 0.f);
          *(u64*)(act + (tt*16 + c16)*SH + nrel) = pack4(v0, v1, v2, v3);
        }
      }
      __syncthreads();   // act ready
      // MLP2: C[no][t] += MFMA(A=w2 rows no, B=act rows t)
      #pragma unroll
      for (int kk = 0; kk < 6; kk++){
        short8 aa[2];
        #pragma unroll
        for (int tt = 0; tt < 2; tt++)
          aa[tt] = *(const short8*)(act + (tt*16 + c16)*SH + kk*32 + quad*8);
        short8 bw[3];
        #pragma unroll
        for (int ntl = 0; ntl < 3; ntl++)
          bw[ntl] = *(const short8*)(w2t + (size_t)(wave*48 + ntl*16 + c16)*768 + ch*192 + kk*32 + quad*8);
        #pragma unroll
        for (int ntl = 0; ntl < 3; ntl++)
          #pragma unroll
          for (int tt = 0; tt < 2; tt++)
            outacc[ntl][tt] = MFMA16(bw[ntl], aa[tt], outacc[ntl][tt]);
      }
    }
    // mlp out bf16 -> hn [t][no] (hn dead: all MLP1 reads finished before last act barrier;
    // other waves' MLP2 only touches act/w2t)
    #pragma unroll
    for (int ntl = 0; ntl < 3; ntl++){
      int no = wave*48 + ntl*16 + quad*4;
      #pragma unroll
      for (int tt = 0; tt < 2; tt++)
        *(u64*)(hn + (tt*16 + c16)*SH + no) =
          pack4(outacc[ntl][tt][0], outacc[ntl][tt][1], outacc[ntl][tt][2], outacc[ntl][tt][3]);
    }
  }
  __syncthreads();

  // ---- out = x + att + mlp + b2 (same rounding path as the two-kernel version)
  #pragma unroll
  for (int it = 0; it < 6; it++){
    int idx = it*256 + tid;
    if (idx < 1440){
      f32x4 v = *(const f32x4*)(x + base + (long)idx*4);
      int row = (int)(((u32)idx * 745655u) >> 25);
      int col4 = (idx - row*45)*4;
      f32x4 bb = *(const f32x4*)(b2 + col4);
      u64 m = *(const u64*)(hn + row*SH + col4);
      #pragma unroll
      for (int e = 0; e < 4; e++){
        int c = col4 + e;
        int h = (c*4370) >> 17;
        int d = c - h*30;
        v[e] += bf2f(att[row*SA + h*32 + d]) + bf2f((ushort_t)(m >> (16*e))) + bb[e];
      }
      *(f32x4*)(out + base + (long)idx*4) = v;
    }
  }
}

extern "C" void kernel_launch(void* const* d_in, const int* in_sizes, int n_in,
                              void* d_out, int out_size, void* d_ws, size_t ws_size,
                              hipStream_t stream) {
  const float* x   = (const float*)d_in[0];
  const float* wq  = (const float*)d_in[1];
  const float* wk  = (const float*)d_in[2];
  const float* wv  = (const float*)d_in[3];
  const float* g1  = (const float*)d_in[4];
  const float* be1 = (const float*)d_in[5];
  const float* g2  = (const float*)d_in[6];
  const float* be2 = (const float*)d_in[7];
  const float* w1  = (const float*)d_in[8];
  const float* b1  = (const float*)d_in[9];
  const float* w2  = (const float*)d_in[10];
  const float* b2  = (const float*)d_in[11];
  ushort_t* ws   = (ushort_t*)d_ws;
  ushort_t* wqkv = ws;
  ushort_t* w1t  = ws + WQKV_ELEMS;
  ushort_t* w2t  = w1t + W1T_ELEMS;
  float* out = (float*)d_out;

  prep_weights<<<256, 256, 0, stream>>>(wq, wk, wv, w1, w2, ws);
  block_kernel<<<4096, 256, 0, stream>>>(x, g1, be1, g2, be2, b1, b2,
                                         wqkv, w1t, w2t, out);
}

// Round 2
// 525.724 us; speedup vs baseline: 1.0767x; 1.0767x over previous
//
#include <hip/hip_runtime.h>

typedef __attribute__((ext_vector_type(8))) short short8;
typedef __attribute__((ext_vector_type(4))) float f32x4;
typedef __attribute__((ext_vector_type(2))) float f32x2;
typedef unsigned short ushort_t;
typedef unsigned int u32;
typedef unsigned long long u64;

#define MFMA16(a,b,c) __builtin_amdgcn_mfma_f32_16x16x32_bf16((a),(b),(c),0,0,0)

__device__ __forceinline__ ushort_t f2bf(float f){
  union { float f; u32 u; } v; v.f = f;
  u32 r = v.u + 0x7fffu + ((v.u >> 16) & 1u);
  return (ushort_t)(r >> 16);
}
__device__ __forceinline__ float bf2f(ushort_t h){
  union { u32 u; float f; } v; v.u = ((u32)h) << 16; return v.f;
}
__device__ __forceinline__ u64 pack4(float a, float b, float c, float d){
  u32 p0 = (u32)f2bf(a) | ((u32)f2bf(b) << 16);
  u32 p1 = (u32)f2bf(c) | ((u32)f2bf(d) << 16);
  return (u64)p0 | ((u64)p1 << 32);
}

template<int CTRL>
__device__ __forceinline__ float dpp_add(float x){
  union { float f; int i; } a, b;
  a.f = x;
  b.i = __builtin_amdgcn_update_dpp(a.i, a.i, CTRL, 0xF, 0xF, false);
  return x + b.f;
}
// 4-lane reduce (xor1, xor2 within quads)
__device__ __forceinline__ float red4_add(float x){
  x = dpp_add<0xB1>(x); x = dpp_add<0x4E>(x);
  return x;
}

// B=4096 T=32 C=180 H=6 HD=30 ; tokens=131072
// ws (ushort): wqkv[6][3][32][192] | w1t[768][192] | w2t[192][768]
#define WQKV_ELEMS (576*192)
#define W1T_ELEMS  (768*192)
#define W2T_ELEMS  (192*768)

#define SH 200   // 400B rows (192 cols + pad): bank stride 4 -> 2-way max (free)
#define SS 40    //  80B rows: attn scratch

__global__ void prep_weights(const float* __restrict__ wq, const float* __restrict__ wk,
                             const float* __restrict__ wv, const float* __restrict__ w1,
                             const float* __restrict__ w2, ushort_t* __restrict__ ws){
  ushort_t* wqkv = ws;
  ushort_t* w1t = ws + WQKV_ELEMS;
  ushort_t* w2t = w1t + W1T_ELEMS;
  int tid = blockIdx.x * blockDim.x + threadIdx.x;
  int stride = gridDim.x * blockDim.x;
  for (int i = tid; i < WQKV_ELEMS; i += stride){
    int k = i % 192; int row = i / 192;
    int d = row & 31; int m = (row >> 5) % 3; int h = row / 96;
    float v = 0.f;
    if (d < 30 && k < 180){
      const float* W = (m == 0) ? wq : ((m == 1) ? wk : wv);
      v = W[(h*180 + k)*30 + d];
    }
    wqkv[i] = f2bf(v);
  }
  for (int i = tid; i < W1T_ELEMS; i += stride){
    int c = i % 192; int n = i / 192;
    float v = (n < 720 && c < 180) ? w1[c*720 + n] : 0.f;
    w1t[i] = f2bf(v);
  }
  for (int i = tid; i < W2T_ELEMS; i += stride){
    int c4 = i % 768; int n = i / 768;
    float v = (n < 180 && c4 < 720) ? w2[c4*180 + n] : 0.f;
    w2t[i] = f2bf(v);
  }
}

// LN over 64 rows: 4 threads/row, 48 cols each (pad zeros included; /180 fixed)
__device__ __forceinline__ void ln_pass(const ushort_t* src, ushort_t* dst,
                                        const float* __restrict__ g,
                                        const float* __restrict__ be, int tid){
  int row = tid >> 2, sub = tid & 3;
  int c0 = sub*48;
  float s1 = 0.f, s2 = 0.f;
  #pragma unroll
  for (int gi = 0; gi < 12; gi++){
    u64 m = *(const u64*)(src + row*SH + c0 + gi*4);
    #pragma unroll
    for (int e = 0; e < 4; e++){
      float v = bf2f((ushort_t)(m >> (16*e)));
      s1 += v; s2 += v*v;
    }
  }
  s1 = red4_add(s1); s2 = red4_add(s2);
  float mu = s1 * (1.f/180.f);
  float rstd = rsqrtf(s2 * (1.f/180.f) - mu*mu + 1e-5f);
  #pragma unroll
  for (int gi = 0; gi < 12; gi++){
    int c = c0 + gi*4;
    if (c < 180){
      u64 m = *(const u64*)(src + row*SH + c);
      f32x4 gg = *(const f32x4*)(g + c);
      f32x4 bb = *(const f32x4*)(be + c);
      float v0 = (bf2f((ushort_t)(m    )) - mu)*rstd*gg.x + bb.x;
      float v1 = (bf2f((ushort_t)(m>>16)) - mu)*rstd*gg.y + bb.y;
      float v2 = (bf2f((ushort_t)(m>>32)) - mu)*rstd*gg.z + bb.z;
      float v3 = (bf2f((ushort_t)(m>>48)) - mu)*rstd*gg.w + bb.w;
      *(u64*)(dst + row*SH + c) = pack4(v0, v1, v2, v3);
    } else {
      *(u64*)(dst + row*SH + c) = 0ull;
    }
  }
}

// ---------------- Fused kernel: 64 tokens (2 batches)/block, 4 waves, 51.2KB LDS
// -> 3 blocks/CU. attn output scatter-written to `out` (fp32); no att LDS buffer.
// All weight loads software-pipelined 1 kk ahead (cur/next register rotation).
__global__ __launch_bounds__(256, 3)
void block_kernel(const float* __restrict__ x,
                  const float* __restrict__ g1, const float* __restrict__ be1,
                  const float* __restrict__ g2, const float* __restrict__ be2,
                  const float* __restrict__ b1, const float* __restrict__ b2,
                  const ushort_t* __restrict__ wqkv, const ushort_t* __restrict__ w1t,
                  const ushort_t* __restrict__ w2t, float* __restrict__ out){
  __shared__ __align__(16) ushort_t regA[64*SH];  // x-stage | attn scratch | x2 | act
  __shared__ __align__(16) ushort_t hn[64*SH];    // LN1 out -> LN2 out -> mlp out

  int tid = threadIdx.x;
  int wave = tid >> 6, lane = tid & 63;
  int quad = lane >> 4, c16 = lane & 15;
  long base = (long)blockIdx.x * 11520;   // 64 tokens * 180

  // ---- stage x -> regA bf16 (cols 180..191 zeroed); 2880 f32x4 + 192 pad u64
  #pragma unroll
  for (int it = 0; it < 12; it++){
    int idx = it*256 + tid;
    if (idx < 2880){
      f32x4 v = *(const f32x4*)(x + base + (long)idx*4);
      int row = (int)(((u32)idx * 745655u) >> 25);   // idx/45
      int col = idx - row*45;
      *(u64*)(regA + row*SH + col*4) = pack4(v.x, v.y, v.z, v.w);
    } else {
      int p = idx - 2880;                 // [0,192)
      int row = (p*21846) >> 16;          // p/3
      int g = p - row*3;
      *(u64*)(regA + row*SH + 180 + g*4) = 0ull;
    }
  }
  __syncthreads();

  ln_pass(regA, hn, g1, be1, tid);
  __syncthreads();

  // ---- attention: 12 jobs (2 batches x 6 heads), 3 per wave; all waves active
  {
    ushort_t* buf0 = regA + wave*(2*32*SS);   // q, then vT
    ushort_t* buf1 = buf0 + 32*SS;            // k, then P
    const float scl = 0.18257418583505537f;   // 30^-0.5

    for (int jj = 0; jj < 3; jj++){
      int j = wave*3 + jj;
      int bb = (j >= 6) ? 1 : 0;
      int head = j - 6*bb;
      const ushort_t* wbase = wqkv + head*(96*192);

      f32x4 accq[2][2], acck[2][2], accv[2][2];
      #pragma unroll
      for (int i = 0; i < 2; i++)
        #pragma unroll
        for (int jx = 0; jx < 2; jx++){ accq[i][jx]=(f32x4)0.f; acck[i][jx]=(f32x4)0.f; accv[i][jx]=(f32x4)0.f; }

      // prefetch kk=0 weight frags
      short8 aqc[2], akc[2], avc[2];
      #pragma unroll
      for (int mt = 0; mt < 2; mt++){
        aqc[mt] = *(const short8*)(wbase + (      mt*16 + c16)*192 + quad*8);
        akc[mt] = *(const short8*)(wbase + (32  + mt*16 + c16)*192 + quad*8);
        avc[mt] = *(const short8*)(wbase + (64  + mt*16 + c16)*192 + quad*8);
      }
      #pragma unroll
      for (int kk = 0; kk < 6; kk++){
        short8 aqn[2], akn[2], avn[2];
        if (kk < 5){
          #pragma unroll
          for (int mt = 0; mt < 2; mt++){
            aqn[mt] = *(const short8*)(wbase + (      mt*16 + c16)*192 + (kk+1)*32 + quad*8);
            akn[mt] = *(const short8*)(wbase + (32  + mt*16 + c16)*192 + (kk+1)*32 + quad*8);
            avn[mt] = *(const short8*)(wbase + (64  + mt*16 + c16)*192 + (kk+1)*32 + quad*8);
          }
        }
        short8 hf[2];
        #pragma unroll
        for (int nt = 0; nt < 2; nt++)
          hf[nt] = *(const short8*)(hn + (bb*32 + nt*16 + c16)*SH + kk*32 + quad*8);
        #pragma unroll
        for (int mt = 0; mt < 2; mt++)
          #pragma unroll
          for (int nt = 0; nt < 2; nt++){
            accq[mt][nt] = MFMA16(aqc[mt], hf[nt], accq[mt][nt]);  // C[d][t] = qT
            acck[mt][nt] = MFMA16(akc[mt], hf[nt], acck[mt][nt]);  // C[d][t] = kT
            accv[mt][nt] = MFMA16(hf[mt], avc[nt], accv[mt][nt]);  // C[t][d] = v
          }
        if (kk < 5){
          #pragma unroll
          for (int mt = 0; mt < 2; mt++){ aqc[mt]=aqn[mt]; akc[mt]=akn[mt]; avc[mt]=avn[mt]; }
        }
      }
      // q,k rowmajor [t][d] into scratch
      #pragma unroll
      for (int mt = 0; mt < 2; mt++)
        #pragma unroll
        for (int nt = 0; nt < 2; nt++){
          *(u64*)(buf0 + (nt*16 + c16)*SS + mt*16 + quad*4) =
            pack4(accq[mt][nt][0], accq[mt][nt][1], accq[mt][nt][2], accq[mt][nt][3]);
          *(u64*)(buf1 + (nt*16 + c16)*SS + mt*16 + quad*4) =
            pack4(acck[mt][nt][0], acck[mt][nt][1], acck[mt][nt][2], acck[mt][nt][3]);
        }
      // S^T = MFMA(A=k, B=q): C[s][t]
      f32x4 sacc[2][2];
      #pragma unroll
      for (int i = 0; i < 2; i++){ sacc[i][0]=(f32x4)0.f; sacc[i][1]=(f32x4)0.f; }
      short8 akf[2], bqf[2];
      #pragma unroll
      for (int mt = 0; mt < 2; mt++) akf[mt] = *(const short8*)(buf1 + (mt*16 + c16)*SS + quad*8);
      #pragma unroll
      for (int nt = 0; nt < 2; nt++) bqf[nt] = *(const short8*)(buf0 + (nt*16 + c16)*SS + quad*8);
      #pragma unroll
      for (int mt = 0; mt < 2; mt++)
        #pragma unroll
        for (int nt = 0; nt < 2; nt++)
          sacc[mt][nt] = MFMA16(akf[mt], bqf[nt], sacc[mt][nt]);
      // softmax: lane owns token t=nt*16+c16; reduce over quads (xor16,32)
      #pragma unroll
      for (int nt = 0; nt < 2; nt++){
        int t = nt*16 + c16;
        float v[8];
        #pragma unroll
        for (int r = 0; r < 4; r++){
          int s0 = quad*4 + r, s1v = 16 + quad*4 + r;
          v[r]   = (s0  > t) ? -1e30f : sacc[0][nt][r]*scl;
          v[4+r] = (s1v > t) ? -1e30f : sacc[1][nt][r]*scl;
        }
        float m = v[0];
        #pragma unroll
        for (int i = 1; i < 8; i++) m = fmaxf(m, v[i]);
        m = fmaxf(m, __shfl_xor(m, 16));
        m = fmaxf(m, __shfl_xor(m, 32));
        float e[8], s = 0.f;
        #pragma unroll
        for (int i = 0; i < 8; i++){ e[i] = __expf(v[i] - m); s += e[i]; }
        s += __shfl_xor(s, 16);
        s += __shfl_xor(s, 32);
        float inv = 1.f / s;
        *(u64*)(buf1 + t*SS +      quad*4) = pack4(e[0]*inv, e[1]*inv, e[2]*inv, e[3]*inv);
        *(u64*)(buf1 + t*SS + 16 + quad*4) = pack4(e[4]*inv, e[5]*inv, e[6]*inv, e[7]*inv);
      }
      // vT [d][t] into buf0 (q consumed)
      #pragma unroll
      for (int mt = 0; mt < 2; mt++)
        #pragma unroll
        for (int nt = 0; nt < 2; nt++)
          *(u64*)(buf0 + (nt*16 + c16)*SS + mt*16 + quad*4) =
            pack4(accv[mt][nt][0], accv[mt][nt][1], accv[mt][nt][2], accv[mt][nt][3]);
      // PV: C[d][t] = MFMA(A=vT, B=P)
      f32x4 oacc[2][2];
      #pragma unroll
      for (int i = 0; i < 2; i++){ oacc[i][0]=(f32x4)0.f; oacc[i][1]=(f32x4)0.f; }
      short8 avf[2], bpf[2];
      #pragma unroll
      for (int mt = 0; mt < 2; mt++) avf[mt] = *(const short8*)(buf0 + (mt*16 + c16)*SS + quad*8);
      #pragma unroll
      for (int nt = 0; nt < 2; nt++) bpf[nt] = *(const short8*)(buf1 + (nt*16 + c16)*SS + quad*8);
      #pragma unroll
      for (int mt = 0; mt < 2; mt++)
        #pragma unroll
        for (int nt = 0; nt < 2; nt++)
          oacc[mt][nt] = MFMA16(avf[mt], bpf[nt], oacc[mt][nt]);
      // scatter att -> out (fp32, 8B-aligned f32x2 pairs). lane: token nt*16+c16,
      // dims d = mt*16 + quad*4 + e ; drop d >= 30 (mt==1 && quad==3 -> e=2,3 invalid)
      #pragma unroll
      for (int mt = 0; mt < 2; mt++)
        #pragma unroll
        for (int nt = 0; nt < 2; nt++){
          long ob = base + (long)(bb*32 + nt*16 + c16)*180 + head*30 + mt*16 + quad*4;
          f32x2 lo; lo.x = oacc[mt][nt][0]; lo.y = oacc[mt][nt][1];
          *(f32x2*)(out + ob) = lo;
          if (mt == 0 || quad < 3){
            f32x2 hi; hi.x = oacc[mt][nt][2]; hi.y = oacc[mt][nt][3];
            *(f32x2*)(out + ob + 2) = hi;
          }
        }
    }
  }
  __syncthreads();

  // ---- x2 = x + att(out) -> regA bf16 ; both streams coalesced f32x4
  #pragma unroll
  for (int it = 0; it < 12; it++){
    int idx = it*256 + tid;
    if (idx < 2880){
      f32x4 v = *(const f32x4*)(x + base + (long)idx*4);
      f32x4 a = *(const f32x4*)(out + base + (long)idx*4);
      int row = (int)(((u32)idx * 745655u) >> 25);
      int col = idx - row*45;
      *(u64*)(regA + row*SH + col*4) = pack4(v.x+a.x, v.y+a.y, v.z+a.z, v.w+a.w);
    } else {
      int p = idx - 2880;
      int row = (p*21846) >> 16;
      int g = p - row*3;
      *(u64*)(regA + row*SH + 180 + g*4) = 0ull;
    }
  }
  __syncthreads();

  ln_pass(regA, hn, g2, be2, tid);
  __syncthreads();

  // ---- MLP: 4 chunks of 192 hidden; act overlays regA (x2 dead after LN2)
  {
    ushort_t* act = regA;
    f32x4 outacc[3][4];
    #pragma unroll
    for (int i = 0; i < 3; i++)
      #pragma unroll
      for (int jx = 0; jx < 4; jx++) outacc[i][jx] = (f32x4)0.f;

    for (int ch = 0; ch < 4; ch++){
      // MLP1: C[n][t] = MFMA(A=w1 rows n, B=hn rows t) ; weights pipelined 1 kk ahead
      f32x4 aacc[3][4];
      #pragma unroll
      for (int i = 0; i < 3; i++)
        #pragma unroll
        for (int jx = 0; jx < 4; jx++) aacc[i][jx] = (f32x4)0.f;
      short8 awc[3];
      #pragma unroll
      for (int mi = 0; mi < 3; mi++)
        awc[mi] = *(const short8*)(w1t + (size_t)(ch*192 + (wave*3+mi)*16 + c16)*192 + quad*8);
      #pragma unroll
      for (int kk = 0; kk < 6; kk++){
        short8 awn[3];
        if (kk < 5){
          #pragma unroll
          for (int mi = 0; mi < 3; mi++)
            awn[mi] = *(const short8*)(w1t + (size_t)(ch*192 + (wave*3+mi)*16 + c16)*192 + (kk+1)*32 + quad*8);
        }
        short8 bh[4];
        #pragma unroll
        for (int tt = 0; tt < 4; tt++)
          bh[tt] = *(const short8*)(hn + (tt*16 + c16)*SH + kk*32 + quad*8);
        #pragma unroll
        for (int mi = 0; mi < 3; mi++)
          #pragma unroll
          for (int tt = 0; tt < 4; tt++)
            aacc[mi][tt] = MFMA16(awc[mi], bh[tt], aacc[mi][tt]);
        if (kk < 5){
          #pragma unroll
          for (int mi = 0; mi < 3; mi++) awc[mi] = awn[mi];
        }
      }
      __syncthreads();   // prev chunk's MLP2 done reading act
      // bias + relu + packed store act[t][n]
      #pragma unroll
      for (int mi = 0; mi < 3; mi++){
        int nrel = (wave*3+mi)*16 + quad*4;
        int nabs = ch*192 + nrel;
        f32x4 bias = (f32x4)0.f;
        if (nabs < 720) bias = *(const f32x4*)(b1 + nabs);
        #pragma unroll
        for (int tt = 0; tt < 4; tt++){
          float v0 = fmaxf(aacc[mi][tt][0] + bias[0], 0.f);
          float v1 = fmaxf(aacc[mi][tt][1] + bias[1], 0.f);
          float v2 = fmaxf(aacc[mi][tt][2] + bias[2], 0.f);
          float v3 = fmaxf(aacc[mi][tt][3] + bias[3], 0.f);
          *(u64*)(act + (tt*16 + c16)*SH + nrel) = pack4(v0, v1, v2, v3);
        }
      }
      __syncthreads();   // act ready
      // MLP2: C[no][t] += MFMA(A=w2 rows no, B=act rows t) ; pipelined
      short8 bwc[3];
      #pragma unroll
      for (int ntl = 0; ntl < 3; ntl++)
        bwc[ntl] = *(const short8*)(w2t + (size_t)(wave*48 + ntl*16 + c16)*768 + ch*192 + quad*8);
      #pragma unroll
      for (int kk = 0; kk < 6; kk++){
        short8 bwn[3];
        if (kk < 5){
          #pragma unroll
          for (int ntl = 0; ntl < 3; ntl++)
            bwn[ntl] = *(const short8*)(w2t + (size_t)(wave*48 + ntl*16 + c16)*768 + ch*192 + (kk+1)*32 + quad*8);
        }
        short8 aa[4];
        #pragma unroll
        for (int tt = 0; tt < 4; tt++)
          aa[tt] = *(const short8*)(act + (tt*16 + c16)*SH + kk*32 + quad*8);
        #pragma unroll
        for (int ntl = 0; ntl < 3; ntl++)
          #pragma unroll
          for (int tt = 0; tt < 4; tt++)
            outacc[ntl][tt] = MFMA16(bwc[ntl], aa[tt], outacc[ntl][tt]);
        if (kk < 5){
          #pragma unroll
          for (int ntl = 0; ntl < 3; ntl++) bwc[ntl] = bwn[ntl];
        }
      }
    }
    // mlp out bf16 -> hn [t][no] (all hn reads finished at last "act ready" barrier)
    #pragma unroll
    for (int ntl = 0; ntl < 3; ntl++){
      int no = wave*48 + ntl*16 + quad*4;
      #pragma unroll
      for (int tt = 0; tt < 4; tt++)
        *(u64*)(hn + (tt*16 + c16)*SH + no) =
          pack4(outacc[ntl][tt][0], outacc[ntl][tt][1], outacc[ntl][tt][2], outacc[ntl][tt][3]);
    }
  }
  __syncthreads();

  // ---- out = x + att(out) + mlp + b2 ; coalesced
  #pragma unroll
  for (int it = 0; it < 12; it++){
    int idx = it*256 + tid;
    if (idx < 2880){
      f32x4 v = *(const f32x4*)(x + base + (long)idx*4);
      f32x4 a = *(const f32x4*)(out + base + (long)idx*4);
      int row = (int)(((u32)idx * 745655u) >> 25);
      int col4 = (idx - row*45)*4;
      f32x4 b2v = *(const f32x4*)(b2 + col4);
      u64 m = *(const u64*)(hn + row*SH + col4);
      v.x += a.x + bf2f((ushort_t)(m      )) + b2v.x;
      v.y += a.y + bf2f((ushort_t)(m >> 16)) + b2v.y;
      v.z += a.z + bf2f((ushort_t)(m >> 32)) + b2v.z;
      v.w += a.w + bf2f((ushort_t)(m >> 48)) + b2v.w;
      *(f32x4*)(out + base + (long)idx*4) = v;
    }
  }
}

extern "C" void kernel_launch(void* const* d_in, const int* in_sizes, int n_in,
                              void* d_out, int out_size, void* d_ws, size_t ws_size,
                              hipStream_t stream) {
  const float* x   = (const float*)d_in[0];
  const float* wq  = (const float*)d_in[1];
  const float* wk  = (const float*)d_in[2];
  const float* wv  = (const float*)d_in[3];
  const float* g1  = (const float*)d_in[4];
  const float* be1 = (const float*)d_in[5];
  const float* g2  = (const float*)d_in[6];
  const float* be2 = (const float*)d_in[7];
  const float* w1  = (const float*)d_in[8];
  const float* b1  = (const float*)d_in[9];
  const float* w2  = (const float*)d_in[10];
  const float* b2  = (const float*)d_in[11];
  ushort_t* ws   = (ushort_t*)d_ws;
  ushort_t* wqkv = ws;
  ushort_t* w1t  = ws + WQKV_ELEMS;
  ushort_t* w2t  = w1t + W1T_ELEMS;
  float* out = (float*)d_out;

  prep_weights<<<256, 256, 0, stream>>>(wq, wk, wv, w1, w2, ws);
  block_kernel<<<2048, 256, 0, stream>>>(x, g1, be1, g2, be2, b1, b2,
                                         wqkv, w1t, w2t, out);
}

// Round 4
// 503.262 us; speedup vs baseline: 1.1247x; 1.0446x over previous
//
#include <hip/hip_runtime.h>

typedef __attribute__((ext_vector_type(8))) short short8;
typedef __attribute__((ext_vector_type(4))) float f32x4;
typedef unsigned short ushort_t;
typedef unsigned int u32;
typedef unsigned long long u64;

#define MFMA16(a,b,c) __builtin_amdgcn_mfma_f32_16x16x32_bf16((a),(b),(c),0,0,0)

__device__ __forceinline__ ushort_t f2bf(float f){
  union { float f; u32 u; } v; v.f = f;
  u32 r = v.u + 0x7fffu + ((v.u >> 16) & 1u);
  return (ushort_t)(r >> 16);
}
__device__ __forceinline__ float bf2f(ushort_t h){
  union { u32 u; float f; } v; v.u = ((u32)h) << 16; return v.f;
}
__device__ __forceinline__ u64 pack4(float a, float b, float c, float d){
  u32 p0 = (u32)f2bf(a) | ((u32)f2bf(b) << 16);
  u32 p1 = (u32)f2bf(c) | ((u32)f2bf(d) << 16);
  return (u64)p0 | ((u64)p1 << 32);
}
// force-materialize a loaded fragment at this program point (defeats load sinking)
__device__ __forceinline__ void pin(short8 &v){ asm volatile("" : "+v"(v)); }

template<int CTRL>
__device__ __forceinline__ float dpp_add(float x){
  union { float f; int i; } a, b;
  a.f = x;
  b.i = __builtin_amdgcn_update_dpp(a.i, a.i, CTRL, 0xF, 0xF, false);
  return x + b.f;
}
// 4-lane reduce (xor1, xor2 within quads)
__device__ __forceinline__ float red4_add(float x){
  x = dpp_add<0xB1>(x); x = dpp_add<0x4E>(x);
  return x;
}

// B=4096 T=32 C=180 H=6 HD=30 ; tokens=131072
// ws (ushort): wqkv[6][3][32][192] | w1t[768][192] | w2t[192][768]
#define WQKV_ELEMS (576*192)
#define W1T_ELEMS  (768*192)
#define W2T_ELEMS  (192*768)

#define SH 200   // 400B rows (192 cols + pad); 16B-stride 25 (odd) -> ~2-way max on b128
#define SS 40    //  80B rows: attn scratch

__global__ void prep_weights(const float* __restrict__ wq, const float* __restrict__ wk,
                             const float* __restrict__ wv, const float* __restrict__ w1,
                             const float* __restrict__ w2, ushort_t* __restrict__ ws){
  ushort_t* wqkv = ws;
  ushort_t* w1t = ws + WQKV_ELEMS;
  ushort_t* w2t = w1t + W1T_ELEMS;
  int tid = blockIdx.x * blockDim.x + threadIdx.x;
  int stride = gridDim.x * blockDim.x;
  for (int i = tid; i < WQKV_ELEMS; i += stride){
    int k = i % 192; int row = i / 192;
    int d = row & 31; int m = (row >> 5) % 3; int h = row / 96;
    float v = 0.f;
    if (d < 30 && k < 180){
      const float* W = (m == 0) ? wq : ((m == 1) ? wk : wv);
      v = W[(h*180 + k)*30 + d];
    }
    wqkv[i] = f2bf(v);
  }
  for (int i = tid; i < W1T_ELEMS; i += stride){
    int c = i % 192; int n = i / 192;
    float v = (n < 720 && c < 180) ? w1[c*720 + n] : 0.f;
    w1t[i] = f2bf(v);
  }
  for (int i = tid; i < W2T_ELEMS; i += stride){
    int c4 = i % 768; int n = i / 768;
    float v = (n < 180 && c4 < 720) ? w2[c4*180 + n] : 0.f;
    w2t[i] = f2bf(v);
  }
}

// ---------------- Fused kernel: 64 tokens (2 batches)/block, 4 waves, 76.8KB LDS.
// W:   per-wave attn scratch -> act     (25.6KB)
// hn:  LN1 out -> x2 bf16 -> LN2 out    (25.6KB)
// att: attn out [t][head*32+d]          (25.6KB)
// x2 fp32 lives in `out` (global) from the x2-phase; MLP epilogue RMWs it.
__global__ __launch_bounds__(256, 2)
void block_kernel(const float* __restrict__ x,
                  const float* __restrict__ g1, const float* __restrict__ be1,
                  const float* __restrict__ g2, const float* __restrict__ be2,
                  const float* __restrict__ b1, const float* __restrict__ b2,
                  const ushort_t* __restrict__ wqkv, const ushort_t* __restrict__ w1t,
                  const ushort_t* __restrict__ w2t, float* __restrict__ out){
  __shared__ __align__(16) ushort_t W[64*SH];
  __shared__ __align__(16) ushort_t hn[64*SH];
  __shared__ __align__(16) ushort_t att[64*SH];

  int tid = threadIdx.x;
  int wave = tid >> 6, lane = tid & 63;
  int quad = lane >> 4, c16 = lane & 15;
  long base = (long)blockIdx.x * 11520;   // 64 tokens * 180

  // ---- LN1 straight from global: thread = (row, sub); 48 cols each, kept in regs
  {
    int row = tid >> 2, sub = tid & 3;
    int c0 = sub*48;
    f32x4 xv[12];
    float s1 = 0.f, s2 = 0.f;
    #pragma unroll
    for (int gi = 0; gi < 12; gi++){
      int c = c0 + gi*4;
      if (c < 180) xv[gi] = *(const f32x4*)(x + base + (long)row*180 + c);
      else         xv[gi] = (f32x4)0.f;
      s1 += xv[gi].x + xv[gi].y + xv[gi].z + xv[gi].w;
      s2 += xv[gi].x*xv[gi].x + xv[gi].y*xv[gi].y + xv[gi].z*xv[gi].z + xv[gi].w*xv[gi].w;
    }
    s1 = red4_add(s1); s2 = red4_add(s2);
    float mu = s1 * (1.f/180.f);
    float rstd = rsqrtf(s2 * (1.f/180.f) - mu*mu + 1e-5f);
    #pragma unroll
    for (int gi = 0; gi < 12; gi++){
      int c = c0 + gi*4;
      if (c < 180){
        f32x4 gg = *(const f32x4*)(g1 + c);
        f32x4 bb = *(const f32x4*)(be1 + c);
        *(u64*)(hn + row*SH + c) = pack4((xv[gi].x - mu)*rstd*gg.x + bb.x,
                                         (xv[gi].y - mu)*rstd*gg.y + bb.y,
                                         (xv[gi].z - mu)*rstd*gg.z + bb.z,
                                         (xv[gi].w - mu)*rstd*gg.w + bb.w);
      } else {
        *(u64*)(hn + row*SH + c) = 0ull;
      }
    }
  }
  __syncthreads();

  // ---- attention: 12 jobs (2 batches x 6 heads), 3 per wave; PV out -> att (own region)
  {
    ushort_t* buf0 = W + wave*(2*32*SS);   // q, then vT
    ushort_t* buf1 = buf0 + 32*SS;         // k, then P
    const float scl = 0.18257418583505537f;  // 30^-0.5

    for (int jj = 0; jj < 3; jj++){
      int j = wave*3 + jj;
      int bb = (j >= 6) ? 1 : 0;
      int head = j - 6*bb;
      const ushort_t* wbase = wqkv + head*(96*192);

      f32x4 accq[2][2], acck[2][2], accv[2][2];
      #pragma unroll
      for (int i = 0; i < 2; i++)
        #pragma unroll
        for (int jx = 0; jx < 2; jx++){ accq[i][jx]=(f32x4)0.f; acck[i][jx]=(f32x4)0.f; accv[i][jx]=(f32x4)0.f; }

      // preload wq/wk for ALL kk, pinned so the loads actually issue up front
      short8 aqw[2][6], akw[2][6];
      #pragma unroll
      for (int mt = 0; mt < 2; mt++)
        #pragma unroll
        for (int kk = 0; kk < 6; kk++){
          aqw[mt][kk] = *(const short8*)(wbase + (      mt*16 + c16)*192 + kk*32 + quad*8);
          akw[mt][kk] = *(const short8*)(wbase + (32  + mt*16 + c16)*192 + kk*32 + quad*8);
          pin(aqw[mt][kk]); pin(akw[mt][kk]);
        }
      // wv rotated 1-deep
      short8 avc[2], avn[2];
      #pragma unroll
      for (int mt = 0; mt < 2; mt++)
        avc[mt] = *(const short8*)(wbase + (64 + mt*16 + c16)*192 + quad*8);
      #pragma unroll
      for (int kk = 0; kk < 6; kk++){
        if (kk < 5){
          #pragma unroll
          for (int mt = 0; mt < 2; mt++)
            avn[mt] = *(const short8*)(wbase + (64 + mt*16 + c16)*192 + (kk+1)*32 + quad*8);
        }
        short8 hf[2];
        #pragma unroll
        for (int nt = 0; nt < 2; nt++)
          hf[nt] = *(const short8*)(hn + (bb*32 + nt*16 + c16)*SH + kk*32 + quad*8);
        #pragma unroll
        for (int mt = 0; mt < 2; mt++)
          #pragma unroll
          for (int nt = 0; nt < 2; nt++){
            accq[mt][nt] = MFMA16(aqw[mt][kk], hf[nt], accq[mt][nt]);  // C[d][t] = qT
            acck[mt][nt] = MFMA16(akw[mt][kk], hf[nt], acck[mt][nt]);  // C[d][t] = kT
            accv[mt][nt] = MFMA16(hf[mt], avc[nt], accv[mt][nt]);      // C[t][d] = v
          }
        if (kk < 5){
          #pragma unroll
          for (int mt = 0; mt < 2; mt++) avc[mt] = avn[mt];
        }
      }
      // q,k rowmajor [t][d] into scratch
      #pragma unroll
      for (int mt = 0; mt < 2; mt++)
        #pragma unroll
        for (int nt = 0; nt < 2; nt++){
          *(u64*)(buf0 + (nt*16 + c16)*SS + mt*16 + quad*4) =
            pack4(accq[mt][nt][0], accq[mt][nt][1], accq[mt][nt][2], accq[mt][nt][3]);
          *(u64*)(buf1 + (nt*16 + c16)*SS + mt*16 + quad*4) =
            pack4(acck[mt][nt][0], acck[mt][nt][1], acck[mt][nt][2], acck[mt][nt][3]);
        }
      // S^T = MFMA(A=k, B=q): C[s][t]
      f32x4 sacc[2][2];
      #pragma unroll
      for (int i = 0; i < 2; i++){ sacc[i][0]=(f32x4)0.f; sacc[i][1]=(f32x4)0.f; }
      short8 akf[2], bqf[2];
      #pragma unroll
      for (int mt = 0; mt < 2; mt++) akf[mt] = *(const short8*)(buf1 + (mt*16 + c16)*SS + quad*8);
      #pragma unroll
      for (int nt = 0; nt < 2; nt++) bqf[nt] = *(const short8*)(buf0 + (nt*16 + c16)*SS + quad*8);
      #pragma unroll
      for (int mt = 0; mt < 2; mt++)
        #pragma unroll
        for (int nt = 0; nt < 2; nt++)
          sacc[mt][nt] = MFMA16(akf[mt], bqf[nt], sacc[mt][nt]);
      // softmax: lane owns token t=nt*16+c16; reduce over quads (xor16,32)
      #pragma unroll
      for (int nt = 0; nt < 2; nt++){
        int t = nt*16 + c16;
        float v[8];
        #pragma unroll
        for (int r = 0; r < 4; r++){
          int s0 = quad*4 + r, s1v = 16 + quad*4 + r;
          v[r]   = (s0  > t) ? -1e30f : sacc[0][nt][r]*scl;
          v[4+r] = (s1v > t) ? -1e30f : sacc[1][nt][r]*scl;
        }
        float m = v[0];
        #pragma unroll
        for (int i = 1; i < 8; i++) m = fmaxf(m, v[i]);
        m = fmaxf(m, __shfl_xor(m, 16));
        m = fmaxf(m, __shfl_xor(m, 32));
        float e[8], s = 0.f;
        #pragma unroll
        for (int i = 0; i < 8; i++){ e[i] = __expf(v[i] - m); s += e[i]; }
        s += __shfl_xor(s, 16);
        s += __shfl_xor(s, 32);
        float inv = 1.f / s;
        *(u64*)(buf1 + t*SS +      quad*4) = pack4(e[0]*inv, e[1]*inv, e[2]*inv, e[3]*inv);
        *(u64*)(buf1 + t*SS + 16 + quad*4) = pack4(e[4]*inv, e[5]*inv, e[6]*inv, e[7]*inv);
      }
      // vT [d][t] into buf0 (q consumed)
      #pragma unroll
      for (int mt = 0; mt < 2; mt++)
        #pragma unroll
        for (int nt = 0; nt < 2; nt++)
          *(u64*)(buf0 + (nt*16 + c16)*SS + mt*16 + quad*4) =
            pack4(accv[mt][nt][0], accv[mt][nt][1], accv[mt][nt][2], accv[mt][nt][3]);
      // PV: C[d][t] = MFMA(A=vT, B=P) -> straight to att (exclusive region)
      f32x4 oacc[2][2];
      #pragma unroll
      for (int i = 0; i < 2; i++){ oacc[i][0]=(f32x4)0.f; oacc[i][1]=(f32x4)0.f; }
      short8 avf[2], bpf[2];
      #pragma unroll
      for (int mt = 0; mt < 2; mt++) avf[mt] = *(const short8*)(buf0 + (mt*16 + c16)*SS + quad*8);
      #pragma unroll
      for (int nt = 0; nt < 2; nt++) bpf[nt] = *(const short8*)(buf1 + (nt*16 + c16)*SS + quad*8);
      #pragma unroll
      for (int mt = 0; mt < 2; mt++)
        #pragma unroll
        for (int nt = 0; nt < 2; nt++){
          oacc[mt][nt] = MFMA16(avf[mt], bpf[nt], oacc[mt][nt]);
          *(u64*)(att + (bb*32 + nt*16 + c16)*SH + head*32 + mt*16 + quad*4) =
            pack4(oacc[mt][nt][0], oacc[mt][nt][1], oacc[mt][nt][2], oacc[mt][nt][3]);
        }
    }
  }
  __syncthreads();

  // ---- x2 = x + att: fp32 -> out (coalesced full lines), bf16 -> hn (LN2 input)
  #pragma unroll
  for (int it = 0; it < 12; it++){
    int idx = it*256 + tid;
    if (idx < 2880){
      f32x4 v = *(const f32x4*)(x + base + (long)idx*4);
      int row = (int)(((u32)idx * 745655u) >> 25);   // idx/45
      int col4 = (idx - row*45)*4;
      #pragma unroll
      for (int e = 0; e < 4; e++){
        int c = col4 + e;
        int h = (c*4370) >> 17;     // c/30
        int d = c - h*30;
        v[e] += bf2f(att[row*SH + h*32 + d]);
      }
      *(f32x4*)(out + base + (long)idx*4) = v;                 // x2 fp32
      *(u64*)(hn + row*SH + col4) = pack4(v.x, v.y, v.z, v.w); // x2 bf16
    } else {
      int p = idx - 2880;
      int row = (p*21846) >> 16;
      int g = p - row*3;
      *(u64*)(hn + row*SH + 180 + g*4) = 0ull;
    }
  }
  __syncthreads();

  // ---- LN2 in-place on hn (thread-private slots; read-all then write-all)
  {
    int row = tid >> 2, sub = tid & 3;
    int c0 = sub*48;
    float s1 = 0.f, s2 = 0.f;
    u64 mv[12];
    #pragma unroll
    for (int gi = 0; gi < 12; gi++){
      mv[gi] = *(const u64*)(hn + row*SH + c0 + gi*4);
      #pragma unroll
      for (int e = 0; e < 4; e++){
        float v = bf2f((ushort_t)(mv[gi] >> (16*e)));
        s1 += v; s2 += v*v;
      }
    }
    s1 = red4_add(s1); s2 = red4_add(s2);
    float mu = s1 * (1.f/180.f);
    float rstd = rsqrtf(s2 * (1.f/180.f) - mu*mu + 1e-5f);
    #pragma unroll
    for (int gi = 0; gi < 12; gi++){
      int c = c0 + gi*4;
      if (c < 180){
        f32x4 gg = *(const f32x4*)(g2 + c);
        f32x4 bb = *(const f32x4*)(be2 + c);
        float v0 = (bf2f((ushort_t)(mv[gi]    )) - mu)*rstd*gg.x + bb.x;
        float v1 = (bf2f((ushort_t)(mv[gi]>>16)) - mu)*rstd*gg.y + bb.y;
        float v2 = (bf2f((ushort_t)(mv[gi]>>32)) - mu)*rstd*gg.z + bb.z;
        float v3 = (bf2f((ushort_t)(mv[gi]>>48)) - mu)*rstd*gg.w + bb.w;
        *(u64*)(hn + row*SH + c) = pack4(v0, v1, v2, v3);
      }
    }
  }
  __syncthreads();

  // ---- MLP: 4 chunks of 192 hidden; act in W (attn scratch dead);
  //      MLP2 computes C[t][no] so the epilogue RMWs `out` directly.
  {
    ushort_t* act = W;
    f32x4 outacc[4][3];   // [t-tile][no-tile]
    #pragma unroll
    for (int i = 0; i < 4; i++)
      #pragma unroll
      for (int jx = 0; jx < 3; jx++) outacc[i][jx] = (f32x4)0.f;

    for (int ch = 0; ch < 4; ch++){
      // MLP1: C[n][t] = MFMA(A=w1 rows n, B=hn rows t); w1 fully preloaded, pinned
      f32x4 aacc[3][4];
      #pragma unroll
      for (int i = 0; i < 3; i++)
        #pragma unroll
        for (int jx = 0; jx < 4; jx++) aacc[i][jx] = (f32x4)0.f;
      short8 aw[3][6];
      #pragma unroll
      for (int mi = 0; mi < 3; mi++)
        #pragma unroll
        for (int kk = 0; kk < 6; kk++){
          aw[mi][kk] = *(const short8*)(w1t + (size_t)(ch*192 + (wave*3+mi)*16 + c16)*192 + kk*32 + quad*8);
          pin(aw[mi][kk]);
        }
      #pragma unroll
      for (int kk = 0; kk < 6; kk++){
        short8 bh[4];
        #pragma unroll
        for (int tt = 0; tt < 4; tt++)
          bh[tt] = *(const short8*)(hn + (tt*16 + c16)*SH + kk*32 + quad*8);
        #pragma unroll
        for (int mi = 0; mi < 3; mi++)
          #pragma unroll
          for (int tt = 0; tt < 4; tt++)
            aacc[mi][tt] = MFMA16(aw[mi][kk], bh[tt], aacc[mi][tt]);
      }
      __syncthreads();   // prev chunk's MLP2 done reading act
      // bias + relu + packed store act[t][n]
      #pragma unroll
      for (int mi = 0; mi < 3; mi++){
        int nrel = (wave*3+mi)*16 + quad*4;
        int nabs = ch*192 + nrel;
        f32x4 bias = (f32x4)0.f;
        if (nabs < 720) bias = *(const f32x4*)(b1 + nabs);
        #pragma unroll
        for (int tt = 0; tt < 4; tt++){
          float v0 = fmaxf(aacc[mi][tt][0] + bias[0], 0.f);
          float v1 = fmaxf(aacc[mi][tt][1] + bias[1], 0.f);
          float v2 = fmaxf(aacc[mi][tt][2] + bias[2], 0.f);
          float v3 = fmaxf(aacc[mi][tt][3] + bias[3], 0.f);
          *(u64*)(act + (tt*16 + c16)*SH + nrel) = pack4(v0, v1, v2, v3);
        }
      }
      __syncthreads();   // act ready
      // MLP2: C[t][no] += MFMA(A=act rows t, B=w2 rows no); w2 preloaded, pinned
      short8 bw[3][6];
      #pragma unroll
      for (int ntl = 0; ntl < 3; ntl++)
        #pragma unroll
        for (int kk = 0; kk < 6; kk++){
          bw[ntl][kk] = *(const short8*)(w2t + (size_t)(wave*48 + ntl*16 + c16)*768 + ch*192 + kk*32 + quad*8);
          pin(bw[ntl][kk]);
        }
      #pragma unroll
      for (int kk = 0; kk < 6; kk++){
        short8 aa[4];
        #pragma unroll
        for (int tt = 0; tt < 4; tt++)
          aa[tt] = *(const short8*)(act + (tt*16 + c16)*SH + kk*32 + quad*8);
        #pragma unroll
        for (int tt = 0; tt < 4; tt++)
          #pragma unroll
          for (int ntl = 0; ntl < 3; ntl++)
            outacc[tt][ntl] = MFMA16(aa[tt], bw[ntl][kk], outacc[tt][ntl]);
      }
    }
    // epilogue: out[t][no] = x2 (already in out) + mlp + b2 ; no barrier needed
    #pragma unroll
    for (int ntl = 0; ntl < 3; ntl++){
      int no = wave*48 + ntl*16 + c16;
      if (no < 180){
        float bias = b2[no];
        #pragma unroll
        for (int tt = 0; tt < 4; tt++){
          #pragma unroll
          for (int r = 0; r < 4; r++){
            long a = base + (long)(tt*16 + quad*4 + r)*180 + no;
            out[a] = out[a] + outacc[tt][ntl][r] + bias;
          }
        }
      }
    }
  }
}

extern "C" void kernel_launch(void* const* d_in, const int* in_sizes, int n_in,
                              void* d_out, int out_size, void* d_ws, size_t ws_size,
                              hipStream_t stream) {
  const float* x   = (const float*)d_in[0];
  const float* wq  = (const float*)d_in[1];
  const float* wk  = (const float*)d_in[2];
  const float* wv  = (const float*)d_in[3];
  const float* g1  = (const float*)d_in[4];
  const float* be1 = (const float*)d_in[5];
  const float* g2  = (const float*)d_in[6];
  const float* be2 = (const float*)d_in[7];
  const float* w1  = (const float*)d_in[8];
  const float* b1  = (const float*)d_in[9];
  const float* w2  = (const float*)d_in[10];
  const float* b2  = (const float*)d_in[11];
  ushort_t* ws   = (ushort_t*)d_ws;
  ushort_t* wqkv = ws;
  ushort_t* w1t  = ws + WQKV_ELEMS;
  ushort_t* w2t  = w1t + W1T_ELEMS;
  float* out = (float*)d_out;

  prep_weights<<<512, 256, 0, stream>>>(wq, wk, wv, w1, w2, ws);
  block_kernel<<<2048, 256, 0, stream>>>(x, g1, be1, g2, be2, b1, b2,
                                         wqkv, w1t, w2t, out);
}